// Round 9
// baseline (2552.799 us; speedup 1.0000x reference)
//
#include <hip/hip_runtime.h>
#include <hip/hip_bf16.h>

typedef __hip_bfloat16 bf16;

// Problem constants: B=64, L=200, D=256, H=8, F=2, d=32
#define PB 64
#define PL 200
#define PD 256
#define PH 8
#define PdH 32

__device__ __forceinline__ float bfu(unsigned short u) {
    return __uint_as_float(((unsigned)u) << 16);
}

// dtype-generic load/store (device buffers may be fp32 or bf16; detected at runtime)
template <typename T> __device__ __forceinline__ float ldf(const T* p);
template <> __device__ __forceinline__ float ldf<float>(const float* p) { return *p; }
template <> __device__ __forceinline__ float ldf<bf16>(const bf16* p) { return __bfloat162float(*p); }
template <typename T> __device__ __forceinline__ void stf(T* p, float v);
template <> __device__ __forceinline__ void stf<float>(float* p, float v) { *p = v; }
template <> __device__ __forceinline__ void stf<bf16>(bf16* p, float v) { *p = __float2bfloat16(v); }

// internal workspace tensors are ALWAYS bf16
__device__ __forceinline__ void load32_bf16(const bf16* p, float* o) {
    const ushort4* p4 = reinterpret_cast<const ushort4*>(p);
    #pragma unroll
    for (int u = 0; u < 8; ++u) {
        ushort4 x = p4[u];
        o[4 * u + 0] = bfu(x.x); o[4 * u + 1] = bfu(x.y);
        o[4 * u + 2] = bfu(x.z); o[4 * u + 3] = bfu(x.w);
    }
}

// ---------------------------------------------------------------------------
// detect: ln_g[0]==1.0.  bf16 -> uint16[0]=0x3F80 ; fp32 -> uint16[0]=0x0000
// ---------------------------------------------------------------------------
__global__ void detect_mode(const unsigned short* lng_raw, int* flag) {
    if (threadIdx.x == 0 && blockIdx.x == 0)
        *flag = (lng_raw[0] == 0x3F80) ? 1 : 0;   // 1 = bf16 buffers
}

// ---------------------------------------------------------------------------
// K1 body: C[M,256] = A[M,256] @ W[256,256] + bias -> bf16 head-split layout
// ---------------------------------------------------------------------------
template <typename T>
__device__ __forceinline__ void proj_body(
    const T* A, const T* W, const T* bias, bf16* out,
    float (*As)[33], float (*Bs)[65])
{
    const int m0 = blockIdx.x * 64, n0 = blockIdx.y * 64;
    const int t = threadIdx.x;
    const int ty = t >> 4, tx = t & 15;
    float acc[4][4] = {};
    for (int k0 = 0; k0 < 256; k0 += 32) {
        for (int i = t; i < 64 * 32; i += 256) {
            int r = i >> 5, c = i & 31;
            As[r][c] = ldf<T>(&A[(size_t)(m0 + r) * 256 + k0 + c]);
        }
        for (int i = t; i < 32 * 64; i += 256) {
            int r = i >> 6, c = i & 63;
            Bs[r][c] = ldf<T>(&W[(size_t)(k0 + r) * 256 + n0 + c]);
        }
        __syncthreads();
        #pragma unroll
        for (int kk = 0; kk < 32; ++kk) {
            float av[4], bv[4];
            #pragma unroll
            for (int i = 0; i < 4; ++i) av[i] = As[ty * 4 + i][kk];
            #pragma unroll
            for (int j = 0; j < 4; ++j) bv[j] = Bs[kk][tx * 4 + j];
            #pragma unroll
            for (int i = 0; i < 4; ++i)
                #pragma unroll
                for (int j = 0; j < 4; ++j) acc[i][j] += av[i] * bv[j];
        }
        __syncthreads();
    }
    #pragma unroll
    for (int i = 0; i < 4; ++i) {
        int m = m0 + ty * 4 + i;
        int b = m / PL, l = m % PL;
        #pragma unroll
        for (int j = 0; j < 4; ++j) {
            int n = n0 + tx * 4 + j;
            int h = n >> 5, dc = n & 31;
            float v = acc[i][j] + ldf<T>(&bias[n]);
            out[(((size_t)b * PH + h) * PL + l) * PdH + dc] = __float2bfloat16(v);
        }
    }
}

__global__ __launch_bounds__(256) void proj_kernel(
    const void* A, const void* W, const void* bias, bf16* out,
    const int* mode, size_t aoff, size_t woff, size_t boff)
{
    __shared__ float As[64][33];
    __shared__ float Bs[32][65];
    if (*mode)
        proj_body<bf16>((const bf16*)A + aoff, (const bf16*)W + woff,
                        (const bf16*)bias + boff, out, As, Bs);
    else
        proj_body<float>((const float*)A + aoff, (const float*)W + woff,
                         (const float*)bias + boff, out, As, Bs);
}

// ---------------------------------------------------------------------------
// K2 body: streams + gate MLP + gate softmax + score softmax + PV
// ---------------------------------------------------------------------------
template <typename T>
__device__ __forceinline__ void fused_body(
    const bf16* Qh, const bf16* Kh, const bf16* Vh,
    const bf16* QPh, const bf16* KPh, const bf16* QAh, const bf16* KAh,
    const T* mask, const T* Wg1, const T* bg1, const T* Wg2, const T* bg2,
    bf16* ctx,
    float (*qside)[8][32], float (*c_lds)[8][200], float (*probs)[200],
    float (*evals)[8], float (*gw)[8])
{
    const int qt = blockIdx.x, h = blockIdx.y, b = blockIdx.z;
    const int q0 = qt * 8;
    const int t = threadIdx.x;
    const size_t bh = (size_t)b * PH + h;
    const size_t FS = (size_t)PB * PH * PL * PdH;  // f-stride in elems

    const bf16* Qs[4] = { Qh + bh * (PL * PdH), QPh + bh * (PL * PdH),
                          QAh + bh * (PL * PdH), QAh + FS + bh * (PL * PdH) };
    const bf16* Ks[4] = { Kh + bh * (PL * PdH), KPh + bh * (PL * PdH),
                          KAh + bh * (PL * PdH), KAh + FS + bh * (PL * PdH) };

    for (int i = t; i < 4 * 8 * 32; i += 256) {
        int s = i >> 8, rem = i & 255, r = rem >> 5, d0 = rem & 31;
        qside[s][r][d0] = __bfloat162float(Qs[s][(size_t)(q0 + r) * PdH + d0]);
    }
    if (t < 32) evals[t >> 3][t & 7] = ldf<T>(&bg2[0]);
    __syncthreads();

    // --- stream scores ---
    for (int k = t; k < PL; k += 256) {
        #pragma unroll
        for (int s = 0; s < 4; ++s) {
            float kv[32];
            load32_bf16(Ks[s] + (size_t)k * PdH, kv);
            #pragma unroll
            for (int r = 0; r < 8; ++r) {
                float a = 0.f;
                #pragma unroll
                for (int d0 = 0; d0 < 32; ++d0) a += kv[d0] * qside[s][r][d0];
                c_lds[s][r][k] = a;
            }
        }
    }
    __syncthreads();

    // --- gate MLP ---
    {
        const int s = t >> 6;
        const int jt = t & 63;
        const int nj = (jt < 8) ? 4 : 3;
        float acc[8][4];
        #pragma unroll
        for (int r = 0; r < 8; ++r)
            #pragma unroll
            for (int jm = 0; jm < 4; ++jm) acc[r][jm] = 0.f;

        for (int k = 0; k < PL; ++k) {
            float wv[4] = {0.f, 0.f, 0.f, 0.f};
            for (int jm = 0; jm < nj; ++jm)
                wv[jm] = ldf<T>(&Wg1[(size_t)k * PL + jt + 64 * jm]);
            float cv[8];
            #pragma unroll
            for (int r = 0; r < 8; ++r) cv[r] = c_lds[s][r][k];
            #pragma unroll
            for (int r = 0; r < 8; ++r)
                #pragma unroll
                for (int jm = 0; jm < 4; ++jm) acc[r][jm] += cv[r] * wv[jm];
        }
        float part[8];
        #pragma unroll
        for (int r = 0; r < 8; ++r) part[r] = 0.f;
        for (int jm = 0; jm < nj; ++jm) {
            int j = jt + 64 * jm;
            float b1 = ldf<T>(&bg1[j]);
            float w2 = ldf<T>(&Wg2[j]);
            #pragma unroll
            for (int r = 0; r < 8; ++r) {
                float e1 = acc[r][jm] + b1;
                e1 = fmaxf(e1, 0.f);
                part[r] += e1 * w2;
            }
        }
        #pragma unroll
        for (int r = 0; r < 8; ++r) {
            #pragma unroll
            for (int off = 32; off >= 1; off >>= 1)
                part[r] += __shfl_xor(part[r], off, 64);
        }
        if ((t & 63) == 0) {
            #pragma unroll
            for (int r = 0; r < 8; ++r) evals[s][r] += part[r];
        }
    }
    __syncthreads();

    // --- gate softmax over 4 streams ---
    if (t < 8) {
        int r = t;
        float m = evals[0][r];
        for (int s = 1; s < 4; ++s) m = fmaxf(m, evals[s][r]);
        float e[4], sum = 0.f;
        for (int s = 0; s < 4; ++s) { e[s] = expf(evals[s][r] - m); sum += e[s]; }
        float inv = 1.f / sum;
        for (int s = 0; s < 4; ++s) gw[s][r] = e[s] * inv;
    }
    __syncthreads();

    // --- combine streams, scale, +mask ---
    for (int k = t; k < PL; k += 256) {
        #pragma unroll
        for (int r = 0; r < 8; ++r) {
            float sc = 0.f;
            #pragma unroll
            for (int s = 0; s < 4; ++s) sc += c_lds[s][r][k] * gw[s][r];
            sc = sc * 0.17677669529663689f
               + ldf<T>(&mask[((size_t)b * PL + (q0 + r)) * PL + k]);
            probs[r][k] = sc;
        }
    }
    __syncthreads();

    // --- softmax over k per row ---
    {
        const int lane = t & 63, w = t >> 6;
        for (int rr = 0; rr < 2; ++rr) {
            const int r = w * 2 + rr;
            float v[4];
            float mx = -1e30f;
            #pragma unroll
            for (int ki = 0; ki < 4; ++ki) {
                int k = lane + 64 * ki;
                v[ki] = (k < PL) ? probs[r][k] : -1e30f;
                mx = fmaxf(mx, v[ki]);
            }
            #pragma unroll
            for (int off = 32; off >= 1; off >>= 1) mx = fmaxf(mx, __shfl_xor(mx, off, 64));
            float sum = 0.f;
            #pragma unroll
            for (int ki = 0; ki < 4; ++ki) {
                int k = lane + 64 * ki;
                if (k < PL) { v[ki] = expf(v[ki] - mx); sum += v[ki]; }
            }
            #pragma unroll
            for (int off = 32; off >= 1; off >>= 1) sum += __shfl_xor(sum, off, 64);
            float inv = 1.f / sum;
            #pragma unroll
            for (int ki = 0; ki < 4; ++ki) {
                int k = lane + 64 * ki;
                if (k < PL) probs[r][k] = v[ki] * inv;
            }
        }
    }
    __syncthreads();

    // --- PV ---
    {
        const int r = t >> 5, dc = t & 31;
        const bf16* vp = Vh + bh * (PL * PdH);
        float a = 0.f;
        for (int k = 0; k < PL; ++k)
            a += probs[r][k] * __bfloat162float(vp[(size_t)k * PdH + dc]);
        ctx[((size_t)b * PL + q0 + r) * PD + h * PdH + dc] = __float2bfloat16(a);
    }
}

__global__ __launch_bounds__(256) void fused_attn_kernel(
    const bf16* Qh, const bf16* Kh, const bf16* Vh,
    const bf16* QPh, const bf16* KPh, const bf16* QAh, const bf16* KAh,
    const void* mask, const void* Wg1, const void* bg1,
    const void* Wg2, const void* bg2, bf16* ctx, const int* mode)
{
    __shared__ float qside[4][8][32];
    __shared__ float c_lds[4][8][200];
    __shared__ float probs[8][200];
    __shared__ float evals[4][8];
    __shared__ float gw[4][8];
    if (*mode)
        fused_body<bf16>(Qh, Kh, Vh, QPh, KPh, QAh, KAh,
                         (const bf16*)mask, (const bf16*)Wg1, (const bf16*)bg1,
                         (const bf16*)Wg2, (const bf16*)bg2, ctx,
                         qside, c_lds, probs, evals, gw);
    else
        fused_body<float>(Qh, Kh, Vh, QPh, KPh, QAh, KAh,
                          (const float*)mask, (const float*)Wg1, (const float*)bg1,
                          (const float*)Wg2, (const float*)bg2, ctx,
                          qside, c_lds, probs, evals, gw);
}

// ---------------------------------------------------------------------------
// K3 body: h = ctx @ Wd + bd + input ; LayerNorm(D) -> out
// ---------------------------------------------------------------------------
template <typename T>
__device__ __forceinline__ void outln_body(
    const bf16* ctxp, const T* inp, const T* Wd, const T* bd,
    const T* lng, const T* lnb, T* out,
    float (*xrow)[256], float (*red)[4])
{
    const size_t row0 = (size_t)blockIdx.x * 8;
    const int t = threadIdx.x, lane = t & 63, w = t >> 6;
    for (int i = t; i < 8 * 256; i += 256) {
        int rr = i >> 8, c = i & 255;
        xrow[rr][c] = __bfloat162float(ctxp[(row0 + rr) * 256 + c]);
    }
    __syncthreads();
    float acc[8] = {};
    for (int k = 0; k < 256; ++k) {
        float wv = ldf<T>(&Wd[(size_t)k * 256 + t]);
        #pragma unroll
        for (int rr = 0; rr < 8; ++rr) acc[rr] += xrow[rr][k] * wv;
    }
    const float bdv = ldf<T>(&bd[t]);
    const float gv = ldf<T>(&lng[t]);
    const float bv = ldf<T>(&lnb[t]);
    for (int rr = 0; rr < 8; ++rr) {
        float hv = acc[rr] + bdv + ldf<T>(&inp[(row0 + rr) * 256 + t]);
        float s = hv;
        #pragma unroll
        for (int off = 32; off >= 1; off >>= 1) s += __shfl_xor(s, off, 64);
        if (lane == 0) red[0][w] = s;
        __syncthreads();
        float mu = (red[0][0] + red[0][1] + red[0][2] + red[0][3]) * (1.f / 256.f);
        float dv = hv - mu;
        float s2 = dv * dv;
        #pragma unroll
        for (int off = 32; off >= 1; off >>= 1) s2 += __shfl_xor(s2, off, 64);
        if (lane == 0) red[1][w] = s2;
        __syncthreads();
        float var = (red[1][0] + red[1][1] + red[1][2] + red[1][3]) * (1.f / 256.f);
        stf<T>(&out[(row0 + rr) * 256 + t], dv * rsqrtf(var + 1e-12f) * gv + bv);
        __syncthreads();
    }
}

__global__ __launch_bounds__(256) void out_ln_kernel(
    const bf16* ctxp, const void* inp, const void* Wd, const void* bd,
    const void* lng, const void* lnb, void* out, const int* mode)
{
    __shared__ float xrow[8][256];
    __shared__ float red[2][4];
    if (*mode)
        outln_body<bf16>(ctxp, (const bf16*)inp, (const bf16*)Wd, (const bf16*)bd,
                         (const bf16*)lng, (const bf16*)lnb, (bf16*)out, xrow, red);
    else
        outln_body<float>(ctxp, (const float*)inp, (const float*)Wd, (const float*)bd,
                          (const float*)lng, (const float*)lnb, (float*)out, xrow, red);
}

// ---------------------------------------------------------------------------
extern "C" void kernel_launch(void* const* d_in, const int* in_sizes, int n_in,
                              void* d_out, int out_size, void* d_ws, size_t ws_size,
                              hipStream_t stream)
{
    (void)in_sizes; (void)n_in; (void)out_size; (void)ws_size;

    int* flag = (int*)d_ws;
    char* arena = (char*)d_ws + 256;
    const size_t SZ = (size_t)PB * PH * PL * PdH * 2;  // 6,553,600 B per [B,H,L,32] bf16
    bf16* Qh  = (bf16*)(arena + 0 * SZ);
    bf16* Kh  = (bf16*)(arena + 1 * SZ);
    bf16* Vh  = (bf16*)(arena + 2 * SZ);
    bf16* QPh = (bf16*)(arena + 3 * SZ);
    bf16* KPh = (bf16*)(arena + 4 * SZ);
    bf16* QAh = (bf16*)(arena + 5 * SZ);  // 2 f-slices
    bf16* KAh = (bf16*)(arena + 7 * SZ);  // 2 f-slices
    bf16* ctx = (bf16*)(arena + 9 * SZ);

    const size_t AS = (size_t)PB * PL * PD;  // attr f-slice elems
    const size_t WS_ = 65536, BS_ = 256;     // Wqa/bqa f-slice elems

    detect_mode<<<1, 64, 0, stream>>>((const unsigned short*)d_in[24], flag);

    dim3 pg(200, 4), pb(256);
    proj_kernel<<<pg, pb, 0, stream>>>(d_in[0], d_in[4],  d_in[5],  Qh,       flag, 0, 0, 0);
    proj_kernel<<<pg, pb, 0, stream>>>(d_in[0], d_in[6],  d_in[7],  Kh,       flag, 0, 0, 0);
    proj_kernel<<<pg, pb, 0, stream>>>(d_in[0], d_in[8],  d_in[9],  Vh,       flag, 0, 0, 0);
    proj_kernel<<<pg, pb, 0, stream>>>(d_in[2], d_in[10], d_in[11], QPh,      flag, 0, 0, 0);
    proj_kernel<<<pg, pb, 0, stream>>>(d_in[2], d_in[12], d_in[13], KPh,      flag, 0, 0, 0);
    proj_kernel<<<pg, pb, 0, stream>>>(d_in[1], d_in[14], d_in[15], QAh,      flag, 0, 0, 0);
    proj_kernel<<<pg, pb, 0, stream>>>(d_in[1], d_in[14], d_in[15], QAh + AS, flag, AS, WS_, BS_);
    proj_kernel<<<pg, pb, 0, stream>>>(d_in[1], d_in[16], d_in[17], KAh,      flag, 0, 0, 0);
    proj_kernel<<<pg, pb, 0, stream>>>(d_in[1], d_in[16], d_in[17], KAh + AS, flag, AS, WS_, BS_);

    fused_attn_kernel<<<dim3(25, 8, 64), 256, 0, stream>>>(
        Qh, Kh, Vh, QPh, KPh, QAh, KAh,
        d_in[3], d_in[18], d_in[19], d_in[20], d_in[21], ctx, flag);

    out_ln_kernel<<<dim3(1600), 256, 0, stream>>>(
        ctx, d_in[0], d_in[22], d_in[23], d_in[24], d_in[25], d_out, flag);
}

// Round 11
// 1109.087 us; speedup vs baseline: 2.3017x; 2.3017x over previous
//
#include <hip/hip_runtime.h>
#include <hip/hip_bf16.h>

typedef __hip_bfloat16 bf16;
typedef __attribute__((ext_vector_type(8))) short s16x8;
typedef __attribute__((ext_vector_type(4))) float f32x4;

// Problem constants: B=64, L=200, D=256, H=8, F=2, d=32
#define PB 64
#define PL 200
#define PD 256
#define PH 8
#define PdH 32
// gate GEMM padded dims
#define GK 224   // K padded (7 x 32)
#define GN 208   // N padded (13 x 16)
#define CSTR 232 // c_bf row stride in bf16 elems (464B: 2-way LDS aliasing = free)

__device__ __forceinline__ float bfu(unsigned short u) {
    return __uint_as_float(((unsigned)u) << 16);
}

// dtype-generic load/store (device buffers fp32 or bf16; runtime-detected)
template <typename T> __device__ __forceinline__ float ldf(const T* p);
template <> __device__ __forceinline__ float ldf<float>(const float* p) { return *p; }
template <> __device__ __forceinline__ float ldf<bf16>(const bf16* p) { return __bfloat162float(*p); }
template <typename T> __device__ __forceinline__ void stf(T* p, float v);
template <> __device__ __forceinline__ void stf<float>(float* p, float v) { *p = v; }
template <> __device__ __forceinline__ void stf<bf16>(bf16* p, float v) { *p = __float2bfloat16(v); }

__device__ __forceinline__ void load32_bf16(const bf16* p, float* o) {
    const ushort4* p4 = reinterpret_cast<const ushort4*>(p);
    #pragma unroll
    for (int u = 0; u < 8; ++u) {
        ushort4 x = p4[u];
        o[4 * u + 0] = bfu(x.x); o[4 * u + 1] = bfu(x.y);
        o[4 * u + 2] = bfu(x.z); o[4 * u + 3] = bfu(x.w);
    }
}

// ---------------------------------------------------------------------------
// detect: ln_g[0]==1.0.  bf16 -> uint16[0]=0x3F80 ; fp32 -> uint16[0]=0x0000
// ---------------------------------------------------------------------------
__global__ void detect_mode(const unsigned short* lng_raw, int* flag) {
    if (threadIdx.x == 0 && blockIdx.x == 0)
        *flag = (lng_raw[0] == 0x3F80) ? 1 : 0;   // 1 = bf16 buffers
}

// ---------------------------------------------------------------------------
// prep_gate: Wg1[200,200] -> Wg1p[GN][GK] bf16 TRANSPOSED (row n, k-contig),
// zero-padded; bg1 -> bg1f[GN] fp32; Wg2 -> w2f[GN] fp32 (pad 0).
// ---------------------------------------------------------------------------
__global__ void prep_gate(const void* Wg1, const void* bg1, const void* Wg2,
                          bf16* Wg1p, float* bg1f, float* w2f, const int* mode)
{
    const int i = blockIdx.x * 256 + threadIdx.x;
    const bool bm = (*mode != 0);
    if (i < GN * GK) {
        int n = i / GK, k = i % GK;
        float v = 0.f;
        if (n < PL && k < PL)
            v = bm ? __bfloat162float(((const bf16*)Wg1)[(size_t)k * PL + n])
                   : ((const float*)Wg1)[(size_t)k * PL + n];
        Wg1p[i] = __float2bfloat16(v);
    } else if (i < GN * GK + GN) {
        int j = i - GN * GK;
        bg1f[j] = (j < PL) ? (bm ? __bfloat162float(((const bf16*)bg1)[j])
                                 : ((const float*)bg1)[j]) : 0.f;
    } else if (i < GN * GK + 2 * GN) {
        int j = i - GN * GK - GN;
        w2f[j] = (j < PL) ? (bm ? __bfloat162float(((const bf16*)Wg2)[j])
                                : ((const float*)Wg2)[j]) : 0.f;
    }
}

// ---------------------------------------------------------------------------
// K1 body: C[M,256] = A[M,256] @ W[256,256] + bias -> bf16 head-split layout
// ---------------------------------------------------------------------------
template <typename T>
__device__ __forceinline__ void proj_body(
    const T* A, const T* W, const T* bias, bf16* out,
    float (*As)[33], float (*Bs)[65])
{
    const int m0 = blockIdx.x * 64, n0 = blockIdx.y * 64;
    const int t = threadIdx.x;
    const int ty = t >> 4, tx = t & 15;
    float acc[4][4] = {};
    for (int k0 = 0; k0 < 256; k0 += 32) {
        for (int i = t; i < 64 * 32; i += 256) {
            int r = i >> 5, c = i & 31;
            As[r][c] = ldf<T>(&A[(size_t)(m0 + r) * 256 + k0 + c]);
        }
        for (int i = t; i < 32 * 64; i += 256) {
            int r = i >> 6, c = i & 63;
            Bs[r][c] = ldf<T>(&W[(size_t)(k0 + r) * 256 + n0 + c]);
        }
        __syncthreads();
        #pragma unroll
        for (int kk = 0; kk < 32; ++kk) {
            float av[4], bv[4];
            #pragma unroll
            for (int i = 0; i < 4; ++i) av[i] = As[ty * 4 + i][kk];
            #pragma unroll
            for (int j = 0; j < 4; ++j) bv[j] = Bs[kk][tx * 4 + j];
            #pragma unroll
            for (int i = 0; i < 4; ++i)
                #pragma unroll
                for (int j = 0; j < 4; ++j) acc[i][j] += av[i] * bv[j];
        }
        __syncthreads();
    }
    #pragma unroll
    for (int i = 0; i < 4; ++i) {
        int m = m0 + ty * 4 + i;
        int b = m / PL, l = m % PL;
        #pragma unroll
        for (int j = 0; j < 4; ++j) {
            int n = n0 + tx * 4 + j;
            int h = n >> 5, dc = n & 31;
            float v = acc[i][j] + ldf<T>(&bias[n]);
            out[(((size_t)b * PH + h) * PL + l) * PdH + dc] = __float2bfloat16(v);
        }
    }
}

__global__ __launch_bounds__(256) void proj_kernel(
    const void* A, const void* W, const void* bias, bf16* out,
    const int* mode, size_t aoff, size_t woff, size_t boff)
{
    __shared__ float As[64][33];
    __shared__ float Bs[32][65];
    if (*mode)
        proj_body<bf16>((const bf16*)A + aoff, (const bf16*)W + woff,
                        (const bf16*)bias + boff, out, As, Bs);
    else
        proj_body<float>((const float*)A + aoff, (const float*)W + woff,
                         (const float*)bias + boff, out, As, Bs);
}

// ---------------------------------------------------------------------------
// K2 body: streams (bf16 LDS) + MFMA gate MLP + gate softmax + softmax + PV
// ---------------------------------------------------------------------------
template <typename T>
__device__ __forceinline__ void fused_body(
    const bf16* Qh, const bf16* Kh, const bf16* Vh,
    const bf16* QPh, const bf16* KPh, const bf16* QAh, const bf16* KAh,
    const T* mask, const T* bg2,
    const bf16* Wg1p, const float* bg1f, const float* w2f,
    bf16* ctx,
    float (*qside)[8][32], bf16 (*c_bf)[CSTR], float (*probs)[200],
    float (*e_part)[32], float (*gw)[8])
{
    const int qt = blockIdx.x, h = blockIdx.y, b = blockIdx.z;
    const int q0 = qt * 8;
    const int t = threadIdx.x;
    const size_t bh = (size_t)b * PH + h;
    const size_t FS = (size_t)PB * PH * PL * PdH;  // f-stride in elems

    const bf16* Qs[4] = { Qh + bh * (PL * PdH), QPh + bh * (PL * PdH),
                          QAh + bh * (PL * PdH), QAh + FS + bh * (PL * PdH) };
    const bf16* Ks[4] = { Kh + bh * (PL * PdH), KPh + bh * (PL * PdH),
                          KAh + bh * (PL * PdH), KAh + FS + bh * (PL * PdH) };

    for (int i = t; i < 4 * 8 * 32; i += 256) {
        int s = i >> 8, rem = i & 255, r = rem >> 5, d0 = rem & 31;
        qside[s][r][d0] = __bfloat162float(Qs[s][(size_t)(q0 + r) * PdH + d0]);
    }
    __syncthreads();

    // --- stream scores -> bf16 c_bf[m = s*8+r][k], K zero-padded to GK ---
    for (int k = t; k < PL; k += 256) {
        #pragma unroll
        for (int s = 0; s < 4; ++s) {
            float kv[32];
            load32_bf16(Ks[s] + (size_t)k * PdH, kv);
            #pragma unroll
            for (int r = 0; r < 8; ++r) {
                float a = 0.f;
                #pragma unroll
                for (int d0 = 0; d0 < 32; ++d0) a += kv[d0] * qside[s][r][d0];
                c_bf[s * 8 + r][k] = __float2bfloat16(a);
            }
        }
    }
    for (int i = t; i < 32 * (GK - PL); i += 256) {
        int m = i / (GK - PL), k = PL + i % (GK - PL);
        c_bf[m][k] = __float2bfloat16(0.f);
    }
    __syncthreads();

    // --- gate MLP via MFMA: E1[32][GN] = c_bf @ Wg1p^T ; relu ; dot w2 ---
    {
        const int w = t >> 6, lane = t & 63;
        const int lrow = lane & 15;       // A row / B col / D col within tile
        const int lk8 = lane >> 4;        // k-subgroup (8 elems each)
        if (lane < 32) e_part[w][lane] = 0.f;
        for (int p = w; p < 26; p += 4) {        // 2 m-tiles x 13 n-tiles
            const int mt = p / 13, nt = p % 13;
            f32x4 acc = {0.f, 0.f, 0.f, 0.f};
            #pragma unroll
            for (int kt = 0; kt < 7; ++kt) {
                s16x8 a = *reinterpret_cast<const s16x8*>(
                    &c_bf[mt * 16 + lrow][kt * 32 + lk8 * 8]);
                s16x8 bb = *reinterpret_cast<const s16x8*>(
                    &Wg1p[(size_t)(nt * 16 + lrow) * GK + kt * 32 + lk8 * 8]);
                acc = __builtin_amdgcn_mfma_f32_16x16x32_bf16(a, bb, acc, 0, 0, 0);
            }
            // D: col n = nt*16 + (lane&15), row = mt*16 + (lane>>4)*4 + reg
            const int n = nt * 16 + lrow;
            const float b1 = bg1f[n];
            const float w2v = w2f[n];
            float part[4];
            #pragma unroll
            for (int rg = 0; rg < 4; ++rg)
                part[rg] = fmaxf(acc[rg] + b1, 0.f) * w2v;
            #pragma unroll
            for (int off = 1; off < 16; off <<= 1)
                #pragma unroll
                for (int rg = 0; rg < 4; ++rg)
                    part[rg] += __shfl_xor(part[rg], off, 64);
            if (lrow == 0) {
                #pragma unroll
                for (int rg = 0; rg < 4; ++rg)
                    e_part[w][mt * 16 + lk8 * 4 + rg] += part[rg];
            }
        }
    }
    __syncthreads();

    // --- gate softmax over 4 streams ---
    if (t < 8) {
        const float bg2v = ldf<T>(&bg2[0]);
        float ev[4];
        #pragma unroll
        for (int s = 0; s < 4; ++s) {
            ev[s] = bg2v;
            #pragma unroll
            for (int w = 0; w < 4; ++w) ev[s] += e_part[w][s * 8 + t];
        }
        float m = ev[0];
        for (int s = 1; s < 4; ++s) m = fmaxf(m, ev[s]);
        float e[4], sum = 0.f;
        for (int s = 0; s < 4; ++s) { e[s] = expf(ev[s] - m); sum += e[s]; }
        float inv = 1.f / sum;
        for (int s = 0; s < 4; ++s) gw[s][t] = e[s] * inv;
    }
    __syncthreads();

    // --- combine streams, scale, +mask ---
    for (int k = t; k < PL; k += 256) {
        #pragma unroll
        for (int r = 0; r < 8; ++r) {
            float sc = 0.f;
            #pragma unroll
            for (int s = 0; s < 4; ++s)
                sc += __bfloat162float(c_bf[s * 8 + r][k]) * gw[s][r];
            sc = sc * 0.17677669529663689f
               + ldf<T>(&mask[((size_t)b * PL + (q0 + r)) * PL + k]);
            probs[r][k] = sc;
        }
    }
    __syncthreads();

    // --- softmax over k per row ---
    {
        const int lane = t & 63, w = t >> 6;
        for (int rr = 0; rr < 2; ++rr) {
            const int r = w * 2 + rr;
            float v[4];
            float mx = -1e30f;
            #pragma unroll
            for (int ki = 0; ki < 4; ++ki) {
                int k = lane + 64 * ki;
                v[ki] = (k < PL) ? probs[r][k] : -1e30f;
                mx = fmaxf(mx, v[ki]);
            }
            #pragma unroll
            for (int off = 32; off >= 1; off >>= 1) mx = fmaxf(mx, __shfl_xor(mx, off, 64));
            float sum = 0.f;
            #pragma unroll
            for (int ki = 0; ki < 4; ++ki) {
                int k = lane + 64 * ki;
                if (k < PL) { v[ki] = expf(v[ki] - mx); sum += v[ki]; }
            }
            #pragma unroll
            for (int off = 32; off >= 1; off >>= 1) sum += __shfl_xor(sum, off, 64);
            float inv = 1.f / sum;
            #pragma unroll
            for (int ki = 0; ki < 4; ++ki) {
                int k = lane + 64 * ki;
                if (k < PL) probs[r][k] = v[ki] * inv;
            }
        }
    }
    __syncthreads();

    // --- PV ---
    {
        const int r = t >> 5, dc = t & 31;
        const bf16* vp = Vh + bh * (PL * PdH);
        float a = 0.f;
        for (int k = 0; k < PL; ++k)
            a += probs[r][k] * __bfloat162float(vp[(size_t)k * PdH + dc]);
        ctx[((size_t)b * PL + q0 + r) * PD + h * PdH + dc] = __float2bfloat16(a);
    }
}

__global__ __launch_bounds__(256) void fused_attn_kernel(
    const bf16* Qh, const bf16* Kh, const bf16* Vh,
    const bf16* QPh, const bf16* KPh, const bf16* QAh, const bf16* KAh,
    const void* mask, const void* bg2,
    const bf16* Wg1p, const float* bg1f, const float* w2f,
    bf16* ctx, const int* mode)
{
    __shared__ float qside[4][8][32];
    __shared__ bf16 c_bf[32][CSTR];
    __shared__ float probs[8][200];
    __shared__ float e_part[4][32];
    __shared__ float gw[4][8];
    if (*mode)
        fused_body<bf16>(Qh, Kh, Vh, QPh, KPh, QAh, KAh,
                         (const bf16*)mask, (const bf16*)bg2,
                         Wg1p, bg1f, w2f, ctx,
                         qside, c_bf, probs, e_part, gw);
    else
        fused_body<float>(Qh, Kh, Vh, QPh, KPh, QAh, KAh,
                          (const float*)mask, (const float*)bg2,
                          Wg1p, bg1f, w2f, ctx,
                          qside, c_bf, probs, e_part, gw);
}

// ---------------------------------------------------------------------------
// K3 body: h = ctx @ Wd + bd + input ; LayerNorm(D) -> out
// ---------------------------------------------------------------------------
template <typename T>
__device__ __forceinline__ void outln_body(
    const bf16* ctxp, const T* inp, const T* Wd, const T* bd,
    const T* lng, const T* lnb, T* out,
    float (*xrow)[256], float (*red)[4])
{
    const size_t row0 = (size_t)blockIdx.x * 8;
    const int t = threadIdx.x, lane = t & 63, w = t >> 6;
    for (int i = t; i < 8 * 256; i += 256) {
        int rr = i >> 8, c = i & 255;
        xrow[rr][c] = __bfloat162float(ctxp[(row0 + rr) * 256 + c]);
    }
    __syncthreads();
    float acc[8] = {};
    for (int k = 0; k < 256; ++k) {
        float wv = ldf<T>(&Wd[(size_t)k * 256 + t]);
        #pragma unroll
        for (int rr = 0; rr < 8; ++rr) acc[rr] += xrow[rr][k] * wv;
    }
    const float bdv = ldf<T>(&bd[t]);
    const float gv = ldf<T>(&lng[t]);
    const float bv = ldf<T>(&lnb[t]);
    for (int rr = 0; rr < 8; ++rr) {
        float hv = acc[rr] + bdv + ldf<T>(&inp[(row0 + rr) * 256 + t]);
        float s = hv;
        #pragma unroll
        for (int off = 32; off >= 1; off >>= 1) s += __shfl_xor(s, off, 64);
        if (lane == 0) red[0][w] = s;
        __syncthreads();
        float mu = (red[0][0] + red[0][1] + red[0][2] + red[0][3]) * (1.f / 256.f);
        float dv = hv - mu;
        float s2 = dv * dv;
        #pragma unroll
        for (int off = 32; off >= 1; off >>= 1) s2 += __shfl_xor(s2, off, 64);
        if (lane == 0) red[1][w] = s2;
        __syncthreads();
        float var = (red[1][0] + red[1][1] + red[1][2] + red[1][3]) * (1.f / 256.f);
        stf<T>(&out[(row0 + rr) * 256 + t], dv * rsqrtf(var + 1e-12f) * gv + bv);
        __syncthreads();
    }
}

__global__ __launch_bounds__(256) void out_ln_kernel(
    const bf16* ctxp, const void* inp, const void* Wd, const void* bd,
    const void* lng, const void* lnb, void* out, const int* mode)
{
    __shared__ float xrow[8][256];
    __shared__ float red[2][4];
    if (*mode)
        outln_body<bf16>(ctxp, (const bf16*)inp, (const bf16*)Wd, (const bf16*)bd,
                         (const bf16*)lng, (const bf16*)lnb, (bf16*)out, xrow, red);
    else
        outln_body<float>(ctxp, (const float*)inp, (const float*)Wd, (const float*)bd,
                          (const float*)lng, (const float*)lnb, (float*)out, xrow, red);
}

// ---------------------------------------------------------------------------
extern "C" void kernel_launch(void* const* d_in, const int* in_sizes, int n_in,
                              void* d_out, int out_size, void* d_ws, size_t ws_size,
                              hipStream_t stream)
{
    (void)in_sizes; (void)n_in; (void)out_size; (void)ws_size;

    int* flag = (int*)d_ws;
    char* arena = (char*)d_ws + 256;
    const size_t SZ = (size_t)PB * PH * PL * PdH * 2;  // 6,553,600 B per [B,H,L,32] bf16
    bf16* Qh  = (bf16*)(arena + 0 * SZ);
    bf16* Kh  = (bf16*)(arena + 1 * SZ);
    bf16* Vh  = (bf16*)(arena + 2 * SZ);
    bf16* QPh = (bf16*)(arena + 3 * SZ);
    bf16* KPh = (bf16*)(arena + 4 * SZ);
    bf16* QAh = (bf16*)(arena + 5 * SZ);  // 2 f-slices
    bf16* KAh = (bf16*)(arena + 7 * SZ);  // 2 f-slices
    bf16* ctx = (bf16*)(arena + 9 * SZ);
    bf16*  Wg1p = (bf16*)(arena + 10 * SZ);
    float* bg1f = (float*)(arena + 10 * SZ + (size_t)GN * GK * 2);
    float* w2f  = (float*)(arena + 10 * SZ + (size_t)GN * GK * 2 + 1024);

    const size_t AS = (size_t)PB * PL * PD;  // attr f-slice elems
    const size_t WS_ = 65536, BS_ = 256;     // Wqa/bqa f-slice elems

    detect_mode<<<1, 64, 0, stream>>>((const unsigned short*)d_in[24], flag);
    prep_gate<<<(GN * GK + 2 * GN + 255) / 256, 256, 0, stream>>>(
        d_in[18], d_in[19], d_in[20], Wg1p, bg1f, w2f, flag);

    dim3 pg(200, 4), pb(256);
    proj_kernel<<<pg, pb, 0, stream>>>(d_in[0], d_in[4],  d_in[5],  Qh,       flag, 0, 0, 0);
    proj_kernel<<<pg, pb, 0, stream>>>(d_in[0], d_in[6],  d_in[7],  Kh,       flag, 0, 0, 0);
    proj_kernel<<<pg, pb, 0, stream>>>(d_in[0], d_in[8],  d_in[9],  Vh,       flag, 0, 0, 0);
    proj_kernel<<<pg, pb, 0, stream>>>(d_in[2], d_in[10], d_in[11], QPh,      flag, 0, 0, 0);
    proj_kernel<<<pg, pb, 0, stream>>>(d_in[2], d_in[12], d_in[13], KPh,      flag, 0, 0, 0);
    proj_kernel<<<pg, pb, 0, stream>>>(d_in[1], d_in[14], d_in[15], QAh,      flag, 0, 0, 0);
    proj_kernel<<<pg, pb, 0, stream>>>(d_in[1], d_in[14], d_in[15], QAh + AS, flag, AS, WS_, BS_);
    proj_kernel<<<pg, pb, 0, stream>>>(d_in[1], d_in[16], d_in[17], KAh,      flag, 0, 0, 0);
    proj_kernel<<<pg, pb, 0, stream>>>(d_in[1], d_in[16], d_in[17], KAh + AS, flag, AS, WS_, BS_);

    fused_attn_kernel<<<dim3(25, 8, 64), 256, 0, stream>>>(
        Qh, Kh, Vh, QPh, KPh, QAh, KAh,
        d_in[3], d_in[21], Wg1p, bg1f, w2f, ctx, flag);

    out_ln_kernel<<<dim3(1600), 256, 0, stream>>>(
        ctx, d_in[0], d_in[22], d_in[23], d_in[24], d_in[25], d_out, flag);
}

// Round 13
// 565.289 us; speedup vs baseline: 4.5159x; 1.9620x over previous
//
#include <hip/hip_runtime.h>
#include <hip/hip_bf16.h>

typedef __hip_bfloat16 bf16;
typedef __attribute__((ext_vector_type(8))) short s16x8;
typedef __attribute__((ext_vector_type(4))) float f32x4;

// Problem constants: B=64, L=200, D=256, H=8, F=2, d=32
#define PB 64
#define PL 200
#define PD 256
#define PH 8
#define PdH 32
// gate GEMM padded dims
#define GK 224   // K padded (7 x 32)
#define GN 208   // N padded (13 x 16)
#define CSTR 232 // c_bf row stride in bf16 elems
#define ASTR 264 // proj A-tile LDS stride (528B: quarter-wave 2-way = free)

__device__ __forceinline__ float bfu(unsigned short u) {
    return __uint_as_float(((unsigned)u) << 16);
}

template <typename T> __device__ __forceinline__ float ldf(const T* p);
template <> __device__ __forceinline__ float ldf<float>(const float* p) { return *p; }
template <> __device__ __forceinline__ float ldf<bf16>(const bf16* p) { return __bfloat162float(*p); }
template <typename T> __device__ __forceinline__ void stf(T* p, float v);
template <> __device__ __forceinline__ void stf<float>(float* p, float v) { *p = v; }
template <> __device__ __forceinline__ void stf<bf16>(bf16* p, float v) { *p = __float2bfloat16(v); }

__device__ __forceinline__ void load32_bf16(const bf16* p, float* o) {
    const ushort4* p4 = reinterpret_cast<const ushort4*>(p);
    #pragma unroll
    for (int u = 0; u < 8; ++u) {
        ushort4 x = p4[u];
        o[4 * u + 0] = bfu(x.x); o[4 * u + 1] = bfu(x.y);
        o[4 * u + 2] = bfu(x.z); o[4 * u + 3] = bfu(x.w);
    }
}

// ---------------------------------------------------------------------------
// detect: ln_g[0]==1.0.  bf16 -> uint16[0]=0x3F80 ; fp32 -> uint16[0]=0x0000
// ---------------------------------------------------------------------------
__global__ void detect_mode(const unsigned short* lng_raw, int* flag) {
    if (threadIdx.x == 0 && blockIdx.x == 0)
        *flag = (lng_raw[0] == 0x3F80) ? 1 : 0;   // 1 = bf16 buffers
}

// ---------------------------------------------------------------------------
// prep_gate: Wg1[200,200] -> Wg1p[GN][GK] bf16 transposed, zero-padded;
// bg1 -> bg1f[GN] fp32; Wg2 -> w2f[GN] fp32.
// ---------------------------------------------------------------------------
__global__ void prep_gate(const void* Wg1, const void* bg1, const void* Wg2,
                          bf16* Wg1p, float* bg1f, float* w2f, const int* mode)
{
    const int i = blockIdx.x * 256 + threadIdx.x;
    const bool bm = (*mode != 0);
    if (i < GN * GK) {
        int n = i / GK, k = i % GK;
        float v = 0.f;
        if (n < PL && k < PL)
            v = bm ? __bfloat162float(((const bf16*)Wg1)[(size_t)k * PL + n])
                   : ((const float*)Wg1)[(size_t)k * PL + n];
        Wg1p[i] = __float2bfloat16(v);
    } else if (i < GN * GK + GN) {
        int j = i - GN * GK;
        bg1f[j] = (j < PL) ? (bm ? __bfloat162float(((const bf16*)bg1)[j])
                                 : ((const float*)bg1)[j]) : 0.f;
    } else if (i < GN * GK + 2 * GN) {
        int j = i - GN * GK - GN;
        w2f[j] = (j < PL) ? (bm ? __bfloat162float(((const bf16*)Wg2)[j])
                                : ((const float*)Wg2)[j]) : 0.f;
    }
}

// ---------------------------------------------------------------------------
// prep_w: 9 projection weights -> bf16 transposed Wp[w][n][k]; biases -> f32.
// weight order: 0 Wq, 1 Wk, 2 Wv, 3 Wqp, 4 Wkp, 5 Wqa0, 6 Wka0, 7 Wqa1, 8 Wka1
// ---------------------------------------------------------------------------
__global__ void prep_w(
    const void* Wq, const void* Wk, const void* Wv,
    const void* Wqp, const void* Wkp, const void* Wqa, const void* Wka,
    const void* bq, const void* bk, const void* bv,
    const void* bqp, const void* bkp, const void* bqa, const void* bka,
    bf16* Wp, float* biasf, const int* mode)
{
    const int i = blockIdx.x * 256 + threadIdx.x;
    const bool bm = (*mode != 0);
    if (i < 9 * 65536) {
        const int wi = i >> 16, r = i & 65535;
        const int n = r >> 8, k = r & 255;
        const void* wp = Wq; size_t off = 0;
        switch (wi) {
            case 1: wp = Wk;  break; case 2: wp = Wv;  break;
            case 3: wp = Wqp; break; case 4: wp = Wkp; break;
            case 5: wp = Wqa; break; case 6: wp = Wka; break;
            case 7: wp = Wqa; off = 65536; break;
            case 8: wp = Wka; off = 65536; break;
            default: break;
        }
        const size_t src = off + (size_t)k * 256 + n;
        float v = bm ? __bfloat162float(((const bf16*)wp)[src])
                     : ((const float*)wp)[src];
        Wp[i] = __float2bfloat16(v);
    } else if (i < 9 * 65536 + 9 * 256) {
        const int j = i - 9 * 65536;
        const int wi = j >> 8, n = j & 255;
        const void* bp = bq; size_t off = 0;
        switch (wi) {
            case 1: bp = bk;  break; case 2: bp = bv;  break;
            case 3: bp = bqp; break; case 4: bp = bkp; break;
            case 5: bp = bqa; break; case 6: bp = bka; break;
            case 7: bp = bqa; off = 256; break;
            case 8: bp = bka; off = 256; break;
            default: break;
        }
        biasf[j] = bm ? __bfloat162float(((const bf16*)bp)[off + n])
                      : ((const float*)bp)[off + n];
    }
}

// ---------------------------------------------------------------------------
// proj_mfma: one block = 64 rows x N=256 of all weights of one source group.
// grid (200, 4): y=0 input->{Q,K,V}, y=1 posem->{QP,KP},
//                y=2 attr_f0->{QA0,KA0}, y=3 attr_f1->{QA1,KA1}
// ---------------------------------------------------------------------------
template <typename T>
__device__ __forceinline__ void stage_a(const T* src, int m0, bf16 (*Alds)[ASTR])
{
    const int t = threadIdx.x;
    for (int i = t; i < 64 * 32; i += 256) {
        const int row = i >> 5, c8 = (i & 31) * 8;
        bf16 tmp[8];
        #pragma unroll
        for (int j = 0; j < 8; ++j)
            tmp[j] = __float2bfloat16(ldf<T>(&src[(size_t)(m0 + row) * 256 + c8 + j]));
        *reinterpret_cast<s16x8*>(&Alds[row][c8]) =
            *reinterpret_cast<const s16x8*>(tmp);
    }
}

__global__ __launch_bounds__(256) void proj_mfma(
    const void* inp, const void* posem, const void* attr,
    const bf16* __restrict__ Wp, const float* __restrict__ biasf,
    bf16* Qh, bf16* Kh, bf16* Vh, bf16* QPh, bf16* KPh,
    bf16* QAh, bf16* KAh, const int* mode)
{
    __shared__ bf16 Alds[64][ASTR];
    const int g = blockIdx.y;
    const int m0 = blockIdx.x * 64;
    const size_t AS = (size_t)PB * PL * PD;  // attr f-slice elems (3,276,800)

    // source select
    const void* src = inp; size_t soff = 0;
    if (g == 1) src = posem;
    else if (g == 2) src = attr;
    else if (g == 3) { src = attr; soff = AS; }

    if (*mode) stage_a<bf16>((const bf16*)src + soff, m0, Alds);
    else       stage_a<float>((const float*)src + soff, m0, Alds);
    __syncthreads();

    const int w0 = (g == 0) ? 0 : (g == 1) ? 3 : (g == 2) ? 5 : 7;
    const int nw = (g == 0) ? 3 : 2;

    const int t = threadIdx.x;
    const int w = t >> 6, lane = t & 63;
    const int lrow = lane & 15, lk8 = lane >> 4;

    bf16* dests[9] = { Qh, Kh, Vh, QPh, KPh, QAh, KAh, QAh, KAh };
    const size_t doffs[9] = { 0, 0, 0, 0, 0, 0, 0, AS, AS };

    for (int wi_i = 0; wi_i < nw; ++wi_i) {
        const int wi = w0 + wi_i;
        f32x4 acc[4][4];
        #pragma unroll
        for (int mt = 0; mt < 4; ++mt)
            #pragma unroll
            for (int nt = 0; nt < 4; ++nt) acc[mt][nt] = (f32x4){0.f, 0.f, 0.f, 0.f};

        #pragma unroll
        for (int kt = 0; kt < 8; ++kt) {
            s16x8 a[4], bb[4];
            #pragma unroll
            for (int mt = 0; mt < 4; ++mt)
                a[mt] = *reinterpret_cast<const s16x8*>(
                    &Alds[mt * 16 + lrow][kt * 32 + lk8 * 8]);
            #pragma unroll
            for (int nt = 0; nt < 4; ++nt) {
                const int n = w * 64 + nt * 16 + lrow;
                bb[nt] = *reinterpret_cast<const s16x8*>(
                    &Wp[(size_t)wi * 65536 + (size_t)n * 256 + kt * 32 + lk8 * 8]);
            }
            #pragma unroll
            for (int mt = 0; mt < 4; ++mt)
                #pragma unroll
                for (int nt = 0; nt < 4; ++nt)
                    acc[mt][nt] = __builtin_amdgcn_mfma_f32_16x16x32_bf16(
                        a[mt], bb[nt], acc[mt][nt], 0, 0, 0);
        }

        bf16* dst = dests[wi] + doffs[wi];
        #pragma unroll
        for (int nt = 0; nt < 4; ++nt) {
            const int n = w * 64 + nt * 16 + lrow;
            const float bia = biasf[wi * 256 + n];
            const int h = n >> 5, dc = n & 31;
            #pragma unroll
            for (int mt = 0; mt < 4; ++mt) {
                #pragma unroll
                for (int rg = 0; rg < 4; ++rg) {
                    const int m = m0 + mt * 16 + lk8 * 4 + rg;
                    const int b = m / PL, l = m % PL;
                    dst[(((size_t)b * PH + h) * PL + l) * PdH + dc] =
                        __float2bfloat16(acc[mt][nt][rg] + bia);
                }
            }
        }
    }
}

// ---------------------------------------------------------------------------
// K2 body: streams (bf16 LDS) + MFMA gate MLP + gate softmax + softmax + PV
// ---------------------------------------------------------------------------
template <typename T>
__device__ __forceinline__ void fused_body(
    const bf16* Qh, const bf16* Kh, const bf16* Vh,
    const bf16* QPh, const bf16* KPh, const bf16* QAh, const bf16* KAh,
    const T* mask, const T* bg2,
    const bf16* Wg1p, const float* bg1f, const float* w2f,
    bf16* ctx,
    float (*qside)[8][32], bf16 (*c_bf)[CSTR], float (*probs)[200],
    float (*e_part)[32], float (*gw)[8])
{
    const int qt = blockIdx.x, h = blockIdx.y, b = blockIdx.z;
    const int q0 = qt * 8;
    const int t = threadIdx.x;
    const size_t bh = (size_t)b * PH + h;
    const size_t FS = (size_t)PB * PH * PL * PdH;  // f-stride in elems

    const bf16* Qs[4] = { Qh + bh * (PL * PdH), QPh + bh * (PL * PdH),
                          QAh + bh * (PL * PdH), QAh + FS + bh * (PL * PdH) };
    const bf16* Ks[4] = { Kh + bh * (PL * PdH), KPh + bh * (PL * PdH),
                          KAh + bh * (PL * PdH), KAh + FS + bh * (PL * PdH) };

    for (int i = t; i < 4 * 8 * 32; i += 256) {
        int s = i >> 8, rem = i & 255, r = rem >> 5, d0 = rem & 31;
        qside[s][r][d0] = __bfloat162float(Qs[s][(size_t)(q0 + r) * PdH + d0]);
    }
    __syncthreads();

    // --- stream scores -> bf16 c_bf[m = s*8+r][k], K zero-padded to GK ---
    for (int k = t; k < PL; k += 256) {
        #pragma unroll
        for (int s = 0; s < 4; ++s) {
            float kv[32];
            load32_bf16(Ks[s] + (size_t)k * PdH, kv);
            #pragma unroll
            for (int r = 0; r < 8; ++r) {
                float a = 0.f;
                #pragma unroll
                for (int d0 = 0; d0 < 32; ++d0) a += kv[d0] * qside[s][r][d0];
                c_bf[s * 8 + r][k] = __float2bfloat16(a);
            }
        }
    }
    for (int i = t; i < 32 * (GK - PL); i += 256) {
        int m = i / (GK - PL), k = PL + i % (GK - PL);
        c_bf[m][k] = __float2bfloat16(0.f);
    }
    __syncthreads();

    // --- gate MLP via MFMA: E1[32][GN] = c_bf @ Wg1p^T ; relu ; dot w2 ---
    {
        const int w = t >> 6, lane = t & 63;
        const int lrow = lane & 15;
        const int lk8 = lane >> 4;
        if (lane < 32) e_part[w][lane] = 0.f;
        for (int p = w; p < 26; p += 4) {        // 2 m-tiles x 13 n-tiles
            const int mt = p / 13, nt = p % 13;
            f32x4 acc = {0.f, 0.f, 0.f, 0.f};
            #pragma unroll
            for (int kt = 0; kt < 7; ++kt) {
                s16x8 a = *reinterpret_cast<const s16x8*>(
                    &c_bf[mt * 16 + lrow][kt * 32 + lk8 * 8]);
                s16x8 bb = *reinterpret_cast<const s16x8*>(
                    &Wg1p[(size_t)(nt * 16 + lrow) * GK + kt * 32 + lk8 * 8]);
                acc = __builtin_amdgcn_mfma_f32_16x16x32_bf16(a, bb, acc, 0, 0, 0);
            }
            const int n = nt * 16 + lrow;
            const float b1 = bg1f[n];
            const float w2v = w2f[n];
            float part[4];
            #pragma unroll
            for (int rg = 0; rg < 4; ++rg)
                part[rg] = fmaxf(acc[rg] + b1, 0.f) * w2v;
            #pragma unroll
            for (int off = 1; off < 16; off <<= 1)
                #pragma unroll
                for (int rg = 0; rg < 4; ++rg)
                    part[rg] += __shfl_xor(part[rg], off, 64);
            if (lrow == 0) {
                #pragma unroll
                for (int rg = 0; rg < 4; ++rg)
                    e_part[w][mt * 16 + lk8 * 4 + rg] += part[rg];
            }
        }
    }
    __syncthreads();

    // --- gate softmax over 4 streams ---
    if (t < 8) {
        const float bg2v = ldf<T>(&bg2[0]);
        float ev[4];
        #pragma unroll
        for (int s = 0; s < 4; ++s) {
            ev[s] = bg2v;
            #pragma unroll
            for (int w = 0; w < 4; ++w) ev[s] += e_part[w][s * 8 + t];
        }
        float m = ev[0];
        for (int s = 1; s < 4; ++s) m = fmaxf(m, ev[s]);
        float e[4], sum = 0.f;
        for (int s = 0; s < 4; ++s) { e[s] = expf(ev[s] - m); sum += e[s]; }
        float inv = 1.f / sum;
        for (int s = 0; s < 4; ++s) gw[s][t] = e[s] * inv;
    }
    __syncthreads();

    // --- combine streams, scale, +mask ---
    for (int k = t; k < PL; k += 256) {
        #pragma unroll
        for (int r = 0; r < 8; ++r) {
            float sc = 0.f;
            #pragma unroll
            for (int s = 0; s < 4; ++s)
                sc += __bfloat162float(c_bf[s * 8 + r][k]) * gw[s][r];
            sc = sc * 0.17677669529663689f
               + ldf<T>(&mask[((size_t)b * PL + (q0 + r)) * PL + k]);
            probs[r][k] = sc;
        }
    }
    __syncthreads();

    // --- softmax over k per row ---
    {
        const int lane = t & 63, w = t >> 6;
        for (int rr = 0; rr < 2; ++rr) {
            const int r = w * 2 + rr;
            float v[4];
            float mx = -1e30f;
            #pragma unroll
            for (int ki = 0; ki < 4; ++ki) {
                int k = lane + 64 * ki;
                v[ki] = (k < PL) ? probs[r][k] : -1e30f;
                mx = fmaxf(mx, v[ki]);
            }
            #pragma unroll
            for (int off = 32; off >= 1; off >>= 1) mx = fmaxf(mx, __shfl_xor(mx, off, 64));
            float sum = 0.f;
            #pragma unroll
            for (int ki = 0; ki < 4; ++ki) {
                int k = lane + 64 * ki;
                if (k < PL) { v[ki] = expf(v[ki] - mx); sum += v[ki]; }
            }
            #pragma unroll
            for (int off = 32; off >= 1; off >>= 1) sum += __shfl_xor(sum, off, 64);
            float inv = 1.f / sum;
            #pragma unroll
            for (int ki = 0; ki < 4; ++ki) {
                int k = lane + 64 * ki;
                if (k < PL) probs[r][k] = v[ki] * inv;
            }
        }
    }
    __syncthreads();

    // --- PV ---
    {
        const int r = t >> 5, dc = t & 31;
        const bf16* vp = Vh + bh * (PL * PdH);
        float a = 0.f;
        for (int k = 0; k < PL; ++k)
            a += probs[r][k] * __bfloat162float(vp[(size_t)k * PdH + dc]);
        ctx[((size_t)b * PL + q0 + r) * PD + h * PdH + dc] = __float2bfloat16(a);
    }
}

__global__ __launch_bounds__(256) void fused_attn_kernel(
    const bf16* Qh, const bf16* Kh, const bf16* Vh,
    const bf16* QPh, const bf16* KPh, const bf16* QAh, const bf16* KAh,
    const void* mask, const void* bg2,
    const bf16* Wg1p, const float* bg1f, const float* w2f,
    bf16* ctx, const int* mode)
{
    __shared__ float qside[4][8][32];
    __shared__ bf16 c_bf[32][CSTR];
    __shared__ float probs[8][200];
    __shared__ float e_part[4][32];
    __shared__ float gw[4][8];
    if (*mode)
        fused_body<bf16>(Qh, Kh, Vh, QPh, KPh, QAh, KAh,
                         (const bf16*)mask, (const bf16*)bg2,
                         Wg1p, bg1f, w2f, ctx,
                         qside, c_bf, probs, e_part, gw);
    else
        fused_body<float>(Qh, Kh, Vh, QPh, KPh, QAh, KAh,
                          (const float*)mask, (const float*)bg2,
                          Wg1p, bg1f, w2f, ctx,
                          qside, c_bf, probs, e_part, gw);
}

// ---------------------------------------------------------------------------
// K3 body: h = ctx @ Wd + bd + input ; LayerNorm(D) -> out
// ---------------------------------------------------------------------------
template <typename T>
__device__ __forceinline__ void outln_body(
    const bf16* ctxp, const T* inp, const T* Wd, const T* bd,
    const T* lng, const T* lnb, T* out,
    float (*xrow)[256], float (*red)[4])
{
    const size_t row0 = (size_t)blockIdx.x * 8;
    const int t = threadIdx.x, lane = t & 63, w = t >> 6;
    for (int i = t; i < 8 * 256; i += 256) {
        int rr = i >> 8, c = i & 255;
        xrow[rr][c] = __bfloat162float(ctxp[(row0 + rr) * 256 + c]);
    }
    __syncthreads();
    float acc[8] = {};
    for (int k = 0; k < 256; ++k) {
        float wv = ldf<T>(&Wd[(size_t)k * 256 + t]);
        #pragma unroll
        for (int rr = 0; rr < 8; ++rr) acc[rr] += xrow[rr][k] * wv;
    }
    const float bdv = ldf<T>(&bd[t]);
    const float gv = ldf<T>(&lng[t]);
    const float bv = ldf<T>(&lnb[t]);
    for (int rr = 0; rr < 8; ++rr) {
        float hv = acc[rr] + bdv + ldf<T>(&inp[(row0 + rr) * 256 + t]);
        float s = hv;
        #pragma unroll
        for (int off = 32; off >= 1; off >>= 1) s += __shfl_xor(s, off, 64);
        if (lane == 0) red[0][w] = s;
        __syncthreads();
        float mu = (red[0][0] + red[0][1] + red[0][2] + red[0][3]) * (1.f / 256.f);
        float dv = hv - mu;
        float s2 = dv * dv;
        #pragma unroll
        for (int off = 32; off >= 1; off >>= 1) s2 += __shfl_xor(s2, off, 64);
        if (lane == 0) red[1][w] = s2;
        __syncthreads();
        float var = (red[1][0] + red[1][1] + red[1][2] + red[1][3]) * (1.f / 256.f);
        stf<T>(&out[(row0 + rr) * 256 + t], dv * rsqrtf(var + 1e-12f) * gv + bv);
        __syncthreads();
    }
}

__global__ __launch_bounds__(256) void out_ln_kernel(
    const bf16* ctxp, const void* inp, const void* Wd, const void* bd,
    const void* lng, const void* lnb, void* out, const int* mode)
{
    __shared__ float xrow[8][256];
    __shared__ float red[2][4];
    if (*mode)
        outln_body<bf16>(ctxp, (const bf16*)inp, (const bf16*)Wd, (const bf16*)bd,
                         (const bf16*)lng, (const bf16*)lnb, (bf16*)out, xrow, red);
    else
        outln_body<float>(ctxp, (const float*)inp, (const float*)Wd, (const float*)bd,
                          (const float*)lng, (const float*)lnb, (float*)out, xrow, red);
}

// ---------------------------------------------------------------------------
extern "C" void kernel_launch(void* const* d_in, const int* in_sizes, int n_in,
                              void* d_out, int out_size, void* d_ws, size_t ws_size,
                              hipStream_t stream)
{
    (void)in_sizes; (void)n_in; (void)out_size; (void)ws_size;

    int* flag = (int*)d_ws;
    char* arena = (char*)d_ws + 256;
    const size_t SZ = (size_t)PB * PH * PL * PdH * 2;  // 6,553,600 B per [B,H,L,32] bf16
    bf16* Qh  = (bf16*)(arena + 0 * SZ);
    bf16* Kh  = (bf16*)(arena + 1 * SZ);
    bf16* Vh  = (bf16*)(arena + 2 * SZ);
    bf16* QPh = (bf16*)(arena + 3 * SZ);
    bf16* KPh = (bf16*)(arena + 4 * SZ);
    bf16* QAh = (bf16*)(arena + 5 * SZ);  // 2 f-slices
    bf16* KAh = (bf16*)(arena + 7 * SZ);  // 2 f-slices
    // ctx region (9*SZ..10*SZ) is double-used: Wp/biasf live only prep->proj,
    // ctx written by K2 strictly after proj completes (stream order).
    bf16*  Wp    = (bf16*)(arena + 9 * SZ);
    float* biasf = (float*)(arena + 9 * SZ + (size_t)9 * 65536 * 2);
    bf16*  ctx   = (bf16*)(arena + 9 * SZ);
    bf16*  Wg1p = (bf16*)(arena + 10 * SZ);
    float* bg1f = (float*)(arena + 10 * SZ + (size_t)GN * GK * 2);
    float* w2f  = (float*)(arena + 10 * SZ + (size_t)GN * GK * 2 + 1024);

    detect_mode<<<1, 64, 0, stream>>>((const unsigned short*)d_in[24], flag);
    prep_gate<<<(GN * GK + 2 * GN + 255) / 256, 256, 0, stream>>>(
        d_in[18], d_in[19], d_in[20], Wg1p, bg1f, w2f, flag);
    prep_w<<<(9 * 65536 + 9 * 256 + 255) / 256, 256, 0, stream>>>(
        d_in[4], d_in[6], d_in[8], d_in[10], d_in[12], d_in[14], d_in[16],
        d_in[5], d_in[7], d_in[9], d_in[11], d_in[13], d_in[15], d_in[17],
        Wp, biasf, flag);

    proj_mfma<<<dim3(200, 4), 256, 0, stream>>>(
        d_in[0], d_in[2], d_in[1], Wp, biasf,
        Qh, Kh, Vh, QPh, KPh, QAh, KAh, flag);

    fused_attn_kernel<<<dim3(25, 8, 64), 256, 0, stream>>>(
        Qh, Kh, Vh, QPh, KPh, QAh, KAh,
        d_in[3], d_in[21], Wg1p, bg1f, w2f, ctx, flag);

    out_ln_kernel<<<dim3(1600), 256, 0, stream>>>(
        ctx, d_in[0], d_in[22], d_in[23], d_in[24], d_in[25], d_out, flag);
}